// Round 6
// baseline (611.973 us; speedup 1.0000x reference)
//
#include <hip/hip_runtime.h>
#include <math.h>

#define TEMP 0.0005f
#define B_    32
#define CMEL  80
#define CTXT  512
#define T1_   1600
#define T2_   400

typedef short short8 __attribute__((ext_vector_type(8)));
typedef float f32x4 __attribute__((ext_vector_type(4)));

__device__ inline unsigned short f2bf(float f) {
    unsigned u = __float_as_uint(f);
    u += 0x7FFF + ((u >> 16) & 1);
    return (unsigned short)(u >> 16);
}
__device__ inline unsigned pack2(float a, float b) {
    return (unsigned)f2bf(a) | ((unsigned)f2bf(b) << 16);
}

// ---------------- speaker-embed bias vectors ----------------
__global__ void bias_kernel(const float* __restrict__ se,
                            const float* __restrict__ Wks, const float* __restrict__ bks,
                            const float* __restrict__ Wqs, const float* __restrict__ bqs,
                            float* __restrict__ kb, float* __restrict__ qb) {
    int tid = blockIdx.x * blockDim.x + threadIdx.x;
    const int nk = B_ * CTXT;
    if (tid < nk) {
        int b = tid / CTXT, c = tid % CTXT;
        const float4* s4 = reinterpret_cast<const float4*>(se + b * CTXT);
        const float4* w4 = reinterpret_cast<const float4*>(Wks + (size_t)c * CTXT);
        float acc = bks[c];
        #pragma unroll 4
        for (int j = 0; j < CTXT / 4; ++j) {
            float4 a = s4[j], w = w4[j];
            acc += a.x * w.x + a.y * w.y + a.z * w.z + a.w * w.w;
        }
        kb[tid] = acc;
    } else if (tid < nk + B_ * CMEL) {
        int t = tid - nk;
        int b = t / CMEL, c = t % CMEL;
        const float4* s4 = reinterpret_cast<const float4*>(se + b * CTXT);
        const float4* w4 = reinterpret_cast<const float4*>(Wqs + (size_t)c * CTXT);
        float acc = bqs[c];
        #pragma unroll 4
        for (int j = 0; j < CTXT / 4; ++j) {
            float4 a = s4[j], w = w4[j];
            acc += a.x * w.x + a.y * w.y + a.z * w.z + a.w * w.w;
        }
        qb[t] = acc;
    }
}

// ---------------- all weight casts in one launch ----------------
__global__ void cast_weights_kernel(
        const float* __restrict__ Wk1, const float* __restrict__ Wk2,
        const float* __restrict__ Wq1, const float* __restrict__ Wq2,
        const float* __restrict__ Wq3,
        unsigned short* __restrict__ Ab1, unsigned short* __restrict__ A2,
        unsigned short* __restrict__ A3, unsigned short* __restrict__ A4,
        unsigned short* __restrict__ A5) {
    int e = blockIdx.x * 256 + threadIdx.x;
    const int n1 = 1572864, n2 = 81920, n3 = 46080, n4 = 12800, n5 = 7680;
    if (e < n1) {
        int co = e / 1536, rem = e - co * 1536;
        int dt = rem >> 9, ci = rem & 511;
        Ab1[e] = f2bf(Wk1[((size_t)co * 512 + ci) * 3 + dt]);
    } else if ((e -= n1) < n2) {
        A2[e] = f2bf(Wk2[e]);
    } else if ((e -= n2) < n3) {
        int co = e / 288, rem = e - co * 288;
        int dt = rem / 96, cc = rem - dt * 96;
        A3[e] = (cc < 80) ? f2bf(Wq1[((size_t)co * 80 + cc) * 3 + dt]) : 0;
    } else if ((e -= n3) < n4) {
        A4[e] = f2bf(Wq2[e]);
    } else if ((e -= n4) < n5) {
        int co = e / 96, cc = e - co * 96;
        A5[e] = (cc < 80) ? f2bf(Wq3[co * 80 + cc]) : 0;
    }
}

// ---------------- cast keys+bias -> Xk[b][t+1][512] bf16 (transposed, padded rows) ----
__global__ void castXk_kernel(const float* __restrict__ keys, const float* __restrict__ kb,
                              unsigned short* __restrict__ Xt) {
    __shared__ float tile[64][65];
    const int b = blockIdx.z;
    const int row0 = blockIdx.x * 64;
    const int ci0 = blockIdx.y * 64;
    const int tid = threadIdx.x;
    #pragma unroll
    for (int i = 0; i < 16; ++i) {
        int linear = i * 256 + tid;
        int ci_l = linear >> 6, t_l = linear & 63;
        int t = row0 + t_l - 1;
        float v = 0.f;
        if (t >= 0 && t < 400)
            v = keys[((size_t)b * 512 + ci0 + ci_l) * 400 + t] + kb[b * 512 + ci0 + ci_l];
        tile[t_l][ci_l] = v;
    }
    __syncthreads();
    #pragma unroll
    for (int i = 0; i < 16; ++i) {
        int linear = i * 256 + tid;
        int t_l = linear >> 6, ci_l = linear & 63;
        int row = row0 + t_l;
        if (row < 456)
            Xt[((size_t)b * 456 + row) * 512 + ci0 + ci_l] = f2bf(tile[t_l][ci_l]);
    }
}

// ---------------- cast queries+bias -> Xq1[b][t+1][96] bf16 (transposed, halo+ch pad) ----
__global__ __launch_bounds__(256) void castXq_kernel(
        const float* __restrict__ q, const float* __restrict__ qb,
        unsigned short* __restrict__ Xq1) {
    __shared__ float tile[80][65];
    const int b = blockIdx.y;
    const int t0 = blockIdx.x * 64;
    const int tid = threadIdx.x;
    if (t0 == 0 && tid < 48)
        ((unsigned*)(Xq1 + (size_t)b * 1602 * 96))[tid] = 0u;
    if (t0 == 1536 && tid < 48)
        ((unsigned*)(Xq1 + ((size_t)b * 1602 + 1601) * 96))[tid] = 0u;
    {
        int tl = tid & 63, c0 = tid >> 6;
        for (int c = c0; c < 80; c += 4)
            tile[c][tl] = q[((size_t)b * 80 + c) * 1600 + t0 + tl] + qb[b * 80 + c];
    }
    __syncthreads();
    int row = tid >> 2, cg = tid & 3;
    int t = t0 + row;
    unsigned* orow = (unsigned*)(Xq1 + ((size_t)b * 1602 + t + 1) * 96 + cg * 24);
    #pragma unroll
    for (int jj = 0; jj < 12; ++jj) {
        int c0 = cg * 24 + jj * 2, c1 = c0 + 1;
        float f0 = (c0 < 80) ? tile[c0][row] : 0.f;
        float f1 = (c1 < 80) ? tile[c1][row] : 0.f;
        orow[jj] = pack2(f0, f1);
    }
}

// ---------------- keys conv1 via bf16 MFMA -> channel-last k1c[b][t][1024] ----------------
__global__ __launch_bounds__(256) void conv1k_mfma(
        const unsigned short* __restrict__ Ab, const unsigned short* __restrict__ Xt,
        const float* __restrict__ bias, unsigned short* __restrict__ k1c) {
    __shared__ short As[3 * 128 * 40];
    __shared__ short Xs[66 * 40];
    const int b = blockIdx.z;
    const int co0 = blockIdx.y * 128;
    const int t0 = blockIdx.x * 64;
    const int tid = threadIdx.x;
    const int lane = tid & 63, w = tid >> 6;
    const int wm = w >> 1, wn = w & 1;
    const int l15 = lane & 15, quad = lane >> 4;
    f32x4 acc[4][2];
    #pragma unroll
    for (int mt = 0; mt < 4; ++mt)
        #pragma unroll
        for (int nt = 0; nt < 2; ++nt)
            acc[mt][nt] = (f32x4){0.f, 0.f, 0.f, 0.f};

    for (int ci0 = 0; ci0 < 512; ci0 += 32) {
        __syncthreads();
        #pragma unroll
        for (int i = 0; i < 6; ++i) {
            int linear = i * 256 + tid;
            int dt = linear >> 9;
            int rem = linear & 511;
            int r = rem >> 2, c16 = rem & 3;
            int4 v = *(const int4*)(Ab + (size_t)(co0 + r) * 1536 + dt * 512 + ci0 + c16 * 8);
            *(int4*)(As + (dt * 128 + r) * 40 + c16 * 8) = v;
        }
        #pragma unroll
        for (int i = 0; i < 2; ++i) {
            int c = i * 256 + tid;
            if (c < 264) {
                int row = c >> 2, c16 = c & 3;
                int4 v = *(const int4*)(Xt + ((size_t)b * 456 + t0 + row) * 512 + ci0 + c16 * 8);
                *(int4*)(Xs + row * 40 + c16 * 8) = v;
            }
        }
        __syncthreads();
        #pragma unroll
        for (int dt = 0; dt < 3; ++dt) {
            short8 af[4], bfr[2];
            #pragma unroll
            for (int mt = 0; mt < 4; ++mt)
                af[mt] = *(const short8*)(As + (dt * 128 + wm * 64 + mt * 16 + l15) * 40 + quad * 8);
            #pragma unroll
            for (int nt = 0; nt < 2; ++nt)
                bfr[nt] = *(const short8*)(Xs + (wn * 32 + nt * 16 + l15 + dt) * 40 + quad * 8);
            #pragma unroll
            for (int mt = 0; mt < 4; ++mt)
                #pragma unroll
                for (int nt = 0; nt < 2; ++nt)
                    acc[mt][nt] = __builtin_amdgcn_mfma_f32_16x16x32_bf16(af[mt], bfr[nt], acc[mt][nt], 0, 0, 0);
        }
    }
    #pragma unroll
    for (int mt = 0; mt < 4; ++mt) {
        int cob = co0 + wm * 64 + mt * 16 + quad * 4;
        float bv[4];
        #pragma unroll
        for (int r = 0; r < 4; ++r) bv[r] = bias[cob + r];
        #pragma unroll
        for (int nt = 0; nt < 2; ++nt) {
            int t = t0 + wn * 32 + nt * 16 + l15;
            if (t >= 400) continue;
            float v0 = fmaxf(acc[mt][nt][0] + bv[0], 0.f);
            float v1 = fmaxf(acc[mt][nt][1] + bv[1], 0.f);
            float v2 = fmaxf(acc[mt][nt][2] + bv[2], 0.f);
            float v3 = fmaxf(acc[mt][nt][3] + bv[3], 0.f);
            uint2 p;
            p.x = pack2(v0, v1);
            p.y = pack2(v2, v3);
            *(uint2*)(k1c + ((size_t)b * 400 + t) * 1024 + cob) = p;
        }
    }
}

// ---------------- generic channel-last 1x1(/k3) conv GEMM via MFMA, no LDS ----------------
template<int MT, int NKC, int DTC, bool RELU, int OMODE, int INW, int OUTW, int N, int NR>
__global__ __launch_bounds__(256) void gemm_cl(
        const unsigned short* __restrict__ A, const unsigned short* __restrict__ X,
        const float* __restrict__ bias, unsigned short* __restrict__ out) {
    const int b = blockIdx.y;
    const int tid = threadIdx.x;
    const int lane = tid & 63, w = tid >> 6;
    const int l15 = lane & 15, quad = lane >> 4;
    const int s = blockIdx.x * 64 + w * 16 + l15;
    const int srow = (s < N) ? s : (N - 1);
    const unsigned short* xb = X + (size_t)b * NR * INW;

    f32x4 acc[MT];
    #pragma unroll
    for (int mt = 0; mt < MT; ++mt) acc[mt] = (f32x4){0.f, 0.f, 0.f, 0.f};

    #pragma unroll
    for (int kc = 0; kc < NKC; ++kc) {
        const int dt = DTC ? (kc / DTC) : 0;
        const int koff = DTC ? ((kc - dt * DTC) * 32) : (kc * 32);
        short8 bfr = *(const short8*)(xb + (size_t)(srow + dt) * INW + koff + quad * 8);
        #pragma unroll
        for (int mt = 0; mt < MT; ++mt) {
            short8 af = *(const short8*)(A + (size_t)(mt * 16 + l15) * (NKC * 32) + kc * 32 + quad * 8);
            acc[mt] = __builtin_amdgcn_mfma_f32_16x16x32_bf16(af, bfr, acc[mt], 0, 0, 0);
        }
    }
    if (s >= N) return;

    float v[MT][4];
    float ss = 0.f;
    #pragma unroll
    for (int mt = 0; mt < MT; ++mt) {
        #pragma unroll
        for (int r = 0; r < 4; ++r) {
            float x = acc[mt][r] + bias[mt * 16 + quad * 4 + r];
            if (RELU) x = fmaxf(x, 0.f);
            v[mt][r] = x;
            if (OMODE >= 2) ss += x * x;
        }
    }
    if (OMODE >= 2) {
        ss += __shfl_xor(ss, 16, 64);
        ss += __shfl_xor(ss, 32, 64);
    }
    unsigned short* orow = out + ((size_t)b * N + s) * OUTW;
    #pragma unroll
    for (int mt = 0; mt < MT; ++mt) {
        uint2 p;
        p.x = pack2(v[mt][0], v[mt][1]);
        p.y = pack2(v[mt][2], v[mt][3]);
        *(uint2*)(orow + mt * 16 + quad * 4) = p;
    }
    if (OMODE == 1 && quad == 0) {
        uint4 z = {0u, 0u, 0u, 0u};
        *(uint4*)(orow + 80) = z;
        *(uint4*)(orow + 88) = z;
    }
    if (OMODE >= 2 && quad == 0) {
        float e80 = (OMODE == 2) ? (-0.5f * ss) : 1.0f;
        float e81 = (OMODE == 2) ? 1.0f : (-0.5f * ss);
        uint4 z0 = {pack2(e80, e81), 0u, 0u, 0u};
        uint4 z1 = {0u, 0u, 0u, 0u};
        *(uint4*)(orow + 80) = z0;
        *(uint4*)(orow + 88) = z1;
    }
}

// ---------------- fused qk MFMA + log_softmax + prior + masked softmax ----------------
// 1 wave per block, 16 t1 rows x 400 s. Second softmax done algebraically:
// attn = e1*(prior+eps)*keep / sum(e1*(prior+eps)*keep), e1 = exp(l - m).
__global__ __launch_bounds__(64) void attn_mfma_kernel(
        const unsigned short* __restrict__ qT, const unsigned short* __restrict__ kT,
        const int* __restrict__ mask, const float* __restrict__ prior,
        float* __restrict__ attn_out, float* __restrict__ lp_out) {
    const int b = blockIdx.y;
    const int t10 = blockIdx.x * 16;
    const int lane = threadIdx.x;
    const int l15 = lane & 15, quad = lane >> 4;

    // keep[s] for this lane's 25 columns (row-independent)
    float keep[25];
    #pragma unroll
    for (int ns = 0; ns < 25; ++ns)
        keep[ns] = mask[b * T2_ + ns * 16 + l15] ? 0.f : 1.f;

    const unsigned short* qrow = qT + ((size_t)b * T1_ + t10 + l15) * 96;
    short8 af[3];
    #pragma unroll
    for (int kc = 0; kc < 3; ++kc)
        af[kc] = *(const short8*)(qrow + kc * 32 + quad * 8);

    f32x4 acc[25];
    #pragma unroll
    for (int ns = 0; ns < 25; ++ns) acc[ns] = (f32x4){0.f, 0.f, 0.f, 0.f};
    const unsigned short* kbase = kT + (size_t)b * T2_ * 96 + l15 * 96 + quad * 8;
    #pragma unroll
    for (int ns = 0; ns < 25; ++ns) {
        #pragma unroll
        for (int kc = 0; kc < 3; ++kc) {
            short8 bf = *(const short8*)(kbase + ns * 16 * 96 + kc * 32);
            acc[ns] = __builtin_amdgcn_mfma_f32_16x16x32_bf16(af[kc], bf, acc[ns], 0, 0, 0);
        }
    }

    const float K2T = 2.0f * TEMP;
    #pragma unroll
    for (int r = 0; r < 4; ++r) {
        const int t1 = t10 + quad * 4 + r;
        const float* prow = prior + ((size_t)b * T1_ + t1) * T2_;
        // issue prior loads early (overlap with reductions)
        float pe[25];
        #pragma unroll
        for (int ns = 0; ns < 25; ++ns) pe[ns] = prow[ns * 16 + l15] + 1e-8f;

        float l[25];
        #pragma unroll
        for (int ns = 0; ns < 25; ++ns) l[ns] = K2T * acc[ns][r];
        float m = l[0];
        #pragma unroll
        for (int ns = 1; ns < 25; ++ns) m = fmaxf(m, l[ns]);
        #pragma unroll
        for (int off = 1; off <= 8; off <<= 1) m = fmaxf(m, __shfl_xor(m, off, 16));
        float e1[25];
        float sum = 0.f;
        #pragma unroll
        for (int ns = 0; ns < 25; ++ns) { float e = __expf(l[ns] - m); e1[ns] = e; sum += e; }
        #pragma unroll
        for (int off = 1; off <= 8; off <<= 1) sum += __shfl_xor(sum, off, 16);
        const float lse = m + __logf(sum);

        float* lpr = lp_out + ((size_t)b * T1_ + t1) * T2_;
        float* atr = attn_out + ((size_t)b * T1_ + t1) * T2_;
        float u[25];
        float sum2 = 0.f;
        #pragma unroll
        for (int ns = 0; ns < 25; ++ns) {
            float lp = l[ns] - lse + __logf(pe[ns]);
            lpr[ns * 16 + l15] = lp;
            float uu = e1[ns] * pe[ns] * keep[ns];
            u[ns] = uu;
            sum2 += uu;
        }
        #pragma unroll
        for (int off = 1; off <= 8; off <<= 1) sum2 += __shfl_xor(sum2, off, 16);
        const float inv = 1.f / sum2;
        #pragma unroll
        for (int ns = 0; ns < 25; ++ns) atr[ns * 16 + l15] = u[ns] * inv;
    }
}

extern "C" void kernel_launch(void* const* d_in, const int* in_sizes, int n_in,
                              void* d_out, int out_size, void* d_ws, size_t ws_size,
                              hipStream_t stream) {
    const float* queries = (const float*)d_in[0];
    const float* keys    = (const float*)d_in[1];
    const int*   mask    = (const int*)d_in[2];
    const float* prior   = (const float*)d_in[3];
    const float* se      = (const float*)d_in[4];
    const float* Wk1 = (const float*)d_in[5];
    const float* bk1 = (const float*)d_in[6];
    const float* Wk2 = (const float*)d_in[7];
    const float* bk2 = (const float*)d_in[8];
    const float* Wq1 = (const float*)d_in[9];
    const float* bq1 = (const float*)d_in[10];
    const float* Wq2 = (const float*)d_in[11];
    const float* bq2 = (const float*)d_in[12];
    const float* Wq3 = (const float*)d_in[13];
    const float* bq3 = (const float*)d_in[14];
    const float* Wks = (const float*)d_in[15];
    const float* bks = (const float*)d_in[16];
    const float* Wqs = (const float*)d_in[17];
    const float* bqs = (const float*)d_in[18];

    float* ws = (float*)d_ws;
    float* kb = ws;
    float* qb = ws + 16384;
    unsigned short* Ab1 = (unsigned short*)(ws + 18944);
    unsigned short* A2  = (unsigned short*)(ws + 805376);
    unsigned short* A3  = (unsigned short*)(ws + 846336);
    unsigned short* A4  = (unsigned short*)(ws + 869376);
    unsigned short* A5  = (unsigned short*)(ws + 875776);
    unsigned short* qT  = (unsigned short*)(ws + 879616);
    unsigned short* kT  = (unsigned short*)(ws + 3337216);
    const size_t D = 3951616;
    unsigned short* Xk  = (unsigned short*)(ws + D);
    unsigned short* k1c = (unsigned short*)(ws + D + 3735552);
    unsigned short* Xq1 = (unsigned short*)(ws + D);
    unsigned short* Xq2 = (unsigned short*)(ws + D + 2460672);
    unsigned short* Xq3 = (unsigned short*)(ws + D);

    float* attn_out = (float*)d_out;
    float* lp_out   = attn_out + (size_t)B_ * T1_ * T2_;

    bias_kernel<<<dim3(74), dim3(256), 0, stream>>>(se, Wks, bks, Wqs, bqs, kb, qb);
    cast_weights_kernel<<<dim3(6724), dim3(256), 0, stream>>>(Wk1, Wk2, Wq1, Wq2, Wq3,
                                                              Ab1, A2, A3, A4, A5);
    // keys path
    castXk_kernel<<<dim3(8, 8, 32), dim3(256), 0, stream>>>(keys, kb, Xk);
    conv1k_mfma<<<dim3(7, 8, 32), dim3(256), 0, stream>>>(Ab1, Xk, bk1, k1c);
    gemm_cl<5, 32, 0, false, 2, 1024, 96, 400, 400>
        <<<dim3(7, 32), 256, 0, stream>>>(A2, k1c, bk2, kT);
    // query path
    castXq_kernel<<<dim3(25, 32), dim3(256), 0, stream>>>(queries, qb, Xq1);
    gemm_cl<10, 9, 3, true, 0, 96, 160, 1600, 1602>
        <<<dim3(25, 32), 256, 0, stream>>>(A3, Xq1, bq1, Xq2);
    gemm_cl<5, 5, 0, true, 1, 160, 96, 1600, 1600>
        <<<dim3(25, 32), 256, 0, stream>>>(A4, Xq2, bq2, Xq3);
    gemm_cl<5, 3, 0, false, 3, 96, 96, 1600, 1600>
        <<<dim3(25, 32), 256, 0, stream>>>(A5, Xq3, bq3, qT);
    // fused attention (1 wave / 16 rows per block)
    attn_mfma_kernel<<<dim3(100, 32), dim3(64), 0, stream>>>(qT, kT, mask, prior, attn_out, lp_out);
}

// Round 7
// 523.712 us; speedup vs baseline: 1.1685x; 1.1685x over previous
//
#include <hip/hip_runtime.h>
#include <math.h>

#define TEMP 0.0005f
#define B_    32
#define CMEL  80
#define CTXT  512
#define T1_   1600
#define T2_   400

typedef short short8 __attribute__((ext_vector_type(8)));
typedef float f32x4 __attribute__((ext_vector_type(4)));

__device__ inline unsigned short f2bf(float f) {
    unsigned u = __float_as_uint(f);
    u += 0x7FFF + ((u >> 16) & 1);
    return (unsigned short)(u >> 16);
}
__device__ inline unsigned pack2(float a, float b) {
    return (unsigned)f2bf(a) | ((unsigned)f2bf(b) << 16);
}
__device__ inline float bf2f(unsigned short v) { return __uint_as_float(((unsigned)v) << 16); }

// ---------------- speaker-embed bias vectors ----------------
__global__ void bias_kernel(const float* __restrict__ se,
                            const float* __restrict__ Wks, const float* __restrict__ bks,
                            const float* __restrict__ Wqs, const float* __restrict__ bqs,
                            float* __restrict__ kb, float* __restrict__ qb) {
    int tid = blockIdx.x * blockDim.x + threadIdx.x;
    const int nk = B_ * CTXT;
    if (tid < nk) {
        int b = tid / CTXT, c = tid % CTXT;
        const float4* s4 = reinterpret_cast<const float4*>(se + b * CTXT);
        const float4* w4 = reinterpret_cast<const float4*>(Wks + (size_t)c * CTXT);
        float acc = bks[c];
        #pragma unroll 4
        for (int j = 0; j < CTXT / 4; ++j) {
            float4 a = s4[j], w = w4[j];
            acc += a.x * w.x + a.y * w.y + a.z * w.z + a.w * w.w;
        }
        kb[tid] = acc;
    } else if (tid < nk + B_ * CMEL) {
        int t = tid - nk;
        int b = t / CMEL, c = t % CMEL;
        const float4* s4 = reinterpret_cast<const float4*>(se + b * CTXT);
        const float4* w4 = reinterpret_cast<const float4*>(Wqs + (size_t)c * CTXT);
        float acc = bqs[c];
        #pragma unroll 4
        for (int j = 0; j < CTXT / 4; ++j) {
            float4 a = s4[j], w = w4[j];
            acc += a.x * w.x + a.y * w.y + a.z * w.z + a.w * w.w;
        }
        qb[t] = acc;
    }
}

// ---------------- all weight casts in one launch ----------------
__global__ void cast_weights_kernel(
        const float* __restrict__ Wk1, const float* __restrict__ Wk2,
        const float* __restrict__ Wq1, const float* __restrict__ Wq2,
        const float* __restrict__ Wq3,
        unsigned short* __restrict__ Ab1, unsigned short* __restrict__ A2,
        unsigned short* __restrict__ A3, unsigned short* __restrict__ A4,
        unsigned short* __restrict__ A5) {
    int e = blockIdx.x * 256 + threadIdx.x;
    const int n1 = 1572864, n2 = 81920, n3 = 46080, n4 = 12800, n5 = 7680;
    if (e < n1) {
        int co = e / 1536, rem = e - co * 1536;
        int dt = rem >> 9, ci = rem & 511;
        Ab1[e] = f2bf(Wk1[((size_t)co * 512 + ci) * 3 + dt]);
    } else if ((e -= n1) < n2) {
        A2[e] = f2bf(Wk2[e]);
    } else if ((e -= n2) < n3) {
        int co = e / 288, rem = e - co * 288;
        int dt = rem / 96, cc = rem - dt * 96;
        A3[e] = (cc < 80) ? f2bf(Wq1[((size_t)co * 80 + cc) * 3 + dt]) : 0;
    } else if ((e -= n3) < n4) {
        A4[e] = f2bf(Wq2[e]);
    } else if ((e -= n4) < n5) {
        int co = e / 96, cc = e - co * 96;
        A5[e] = (cc < 80) ? f2bf(Wq3[co * 80 + cc]) : 0;
    }
}

// ---------------- cast keys+bias -> Xk[b][t+1][512] bf16 (transposed, padded rows) ----
__global__ void castXk_kernel(const float* __restrict__ keys, const float* __restrict__ kb,
                              unsigned short* __restrict__ Xt) {
    __shared__ float tile[64][65];
    const int b = blockIdx.z;
    const int row0 = blockIdx.x * 64;
    const int ci0 = blockIdx.y * 64;
    const int tid = threadIdx.x;
    #pragma unroll
    for (int i = 0; i < 16; ++i) {
        int linear = i * 256 + tid;
        int ci_l = linear >> 6, t_l = linear & 63;
        int t = row0 + t_l - 1;
        float v = 0.f;
        if (t >= 0 && t < 400)
            v = keys[((size_t)b * 512 + ci0 + ci_l) * 400 + t] + kb[b * 512 + ci0 + ci_l];
        tile[t_l][ci_l] = v;
    }
    __syncthreads();
    #pragma unroll
    for (int i = 0; i < 16; ++i) {
        int linear = i * 256 + tid;
        int t_l = linear >> 6, ci_l = linear & 63;
        int row = row0 + t_l;
        if (row < 456)
            Xt[((size_t)b * 456 + row) * 512 + ci0 + ci_l] = f2bf(tile[t_l][ci_l]);
    }
}

// ---------------- cast queries+bias -> Xq1[b][t+1][96] bf16 (transposed, halo+ch pad) ----
__global__ __launch_bounds__(256) void castXq_kernel(
        const float* __restrict__ q, const float* __restrict__ qb,
        unsigned short* __restrict__ Xq1) {
    __shared__ float tile[80][65];
    const int b = blockIdx.y;
    const int t0 = blockIdx.x * 64;
    const int tid = threadIdx.x;
    if (t0 == 0 && tid < 48)
        ((unsigned*)(Xq1 + (size_t)b * 1602 * 96))[tid] = 0u;
    if (t0 == 1536 && tid < 48)
        ((unsigned*)(Xq1 + ((size_t)b * 1602 + 1601) * 96))[tid] = 0u;
    {
        int tl = tid & 63, c0 = tid >> 6;
        for (int c = c0; c < 80; c += 4)
            tile[c][tl] = q[((size_t)b * 80 + c) * 1600 + t0 + tl] + qb[b * 80 + c];
    }
    __syncthreads();
    int row = tid >> 2, cg = tid & 3;
    int t = t0 + row;
    unsigned* orow = (unsigned*)(Xq1 + ((size_t)b * 1602 + t + 1) * 96 + cg * 24);
    #pragma unroll
    for (int jj = 0; jj < 12; ++jj) {
        int c0 = cg * 24 + jj * 2, c1 = c0 + 1;
        float f0 = (c0 < 80) ? tile[c0][row] : 0.f;
        float f1 = (c1 < 80) ? tile[c1][row] : 0.f;
        orow[jj] = pack2(f0, f1);
    }
}

// ---------------- keys conv1 via bf16 MFMA -> channel-last k1c[b][t][1024] ----------------
__global__ __launch_bounds__(256) void conv1k_mfma(
        const unsigned short* __restrict__ Ab, const unsigned short* __restrict__ Xt,
        const float* __restrict__ bias, unsigned short* __restrict__ k1c) {
    __shared__ short As[3 * 128 * 40];
    __shared__ short Xs[66 * 40];
    const int b = blockIdx.z;
    const int co0 = blockIdx.y * 128;
    const int t0 = blockIdx.x * 64;
    const int tid = threadIdx.x;
    const int lane = tid & 63, w = tid >> 6;
    const int wm = w >> 1, wn = w & 1;
    const int l15 = lane & 15, quad = lane >> 4;
    f32x4 acc[4][2];
    #pragma unroll
    for (int mt = 0; mt < 4; ++mt)
        #pragma unroll
        for (int nt = 0; nt < 2; ++nt)
            acc[mt][nt] = (f32x4){0.f, 0.f, 0.f, 0.f};

    for (int ci0 = 0; ci0 < 512; ci0 += 32) {
        __syncthreads();
        #pragma unroll
        for (int i = 0; i < 6; ++i) {
            int linear = i * 256 + tid;
            int dt = linear >> 9;
            int rem = linear & 511;
            int r = rem >> 2, c16 = rem & 3;
            int4 v = *(const int4*)(Ab + (size_t)(co0 + r) * 1536 + dt * 512 + ci0 + c16 * 8);
            *(int4*)(As + (dt * 128 + r) * 40 + c16 * 8) = v;
        }
        #pragma unroll
        for (int i = 0; i < 2; ++i) {
            int c = i * 256 + tid;
            if (c < 264) {
                int row = c >> 2, c16 = c & 3;
                int4 v = *(const int4*)(Xt + ((size_t)b * 456 + t0 + row) * 512 + ci0 + c16 * 8);
                *(int4*)(Xs + row * 40 + c16 * 8) = v;
            }
        }
        __syncthreads();
        #pragma unroll
        for (int dt = 0; dt < 3; ++dt) {
            short8 af[4], bfr[2];
            #pragma unroll
            for (int mt = 0; mt < 4; ++mt)
                af[mt] = *(const short8*)(As + (dt * 128 + wm * 64 + mt * 16 + l15) * 40 + quad * 8);
            #pragma unroll
            for (int nt = 0; nt < 2; ++nt)
                bfr[nt] = *(const short8*)(Xs + (wn * 32 + nt * 16 + l15 + dt) * 40 + quad * 8);
            #pragma unroll
            for (int mt = 0; mt < 4; ++mt)
                #pragma unroll
                for (int nt = 0; nt < 2; ++nt)
                    acc[mt][nt] = __builtin_amdgcn_mfma_f32_16x16x32_bf16(af[mt], bfr[nt], acc[mt][nt], 0, 0, 0);
        }
    }
    #pragma unroll
    for (int mt = 0; mt < 4; ++mt) {
        int cob = co0 + wm * 64 + mt * 16 + quad * 4;
        float bv[4];
        #pragma unroll
        for (int r = 0; r < 4; ++r) bv[r] = bias[cob + r];
        #pragma unroll
        for (int nt = 0; nt < 2; ++nt) {
            int t = t0 + wn * 32 + nt * 16 + l15;
            if (t >= 400) continue;
            float v0 = fmaxf(acc[mt][nt][0] + bv[0], 0.f);
            float v1 = fmaxf(acc[mt][nt][1] + bv[1], 0.f);
            float v2 = fmaxf(acc[mt][nt][2] + bv[2], 0.f);
            float v3 = fmaxf(acc[mt][nt][3] + bv[3], 0.f);
            uint2 p;
            p.x = pack2(v0, v1);
            p.y = pack2(v2, v3);
            *(uint2*)(k1c + ((size_t)b * 400 + t) * 1024 + cob) = p;
        }
    }
}

// ---------------- generic channel-last 1x1(/k3) conv GEMM via MFMA, no LDS ----------------
template<int MT, int NKC, int DTC, bool RELU, int OMODE, int INW, int OUTW, int N, int NR>
__global__ __launch_bounds__(256) void gemm_cl(
        const unsigned short* __restrict__ A, const unsigned short* __restrict__ X,
        const float* __restrict__ bias, unsigned short* __restrict__ out) {
    const int b = blockIdx.y;
    const int tid = threadIdx.x;
    const int lane = tid & 63, w = tid >> 6;
    const int l15 = lane & 15, quad = lane >> 4;
    const int s = blockIdx.x * 64 + w * 16 + l15;
    const int srow = (s < N) ? s : (N - 1);
    const unsigned short* xb = X + (size_t)b * NR * INW;

    f32x4 acc[MT];
    #pragma unroll
    for (int mt = 0; mt < MT; ++mt) acc[mt] = (f32x4){0.f, 0.f, 0.f, 0.f};

    #pragma unroll
    for (int kc = 0; kc < NKC; ++kc) {
        const int dt = DTC ? (kc / DTC) : 0;
        const int koff = DTC ? ((kc - dt * DTC) * 32) : (kc * 32);
        short8 bfr = *(const short8*)(xb + (size_t)(srow + dt) * INW + koff + quad * 8);
        #pragma unroll
        for (int mt = 0; mt < MT; ++mt) {
            short8 af = *(const short8*)(A + (size_t)(mt * 16 + l15) * (NKC * 32) + kc * 32 + quad * 8);
            acc[mt] = __builtin_amdgcn_mfma_f32_16x16x32_bf16(af, bfr, acc[mt], 0, 0, 0);
        }
    }
    if (s >= N) return;

    float v[MT][4];
    float ss = 0.f;
    #pragma unroll
    for (int mt = 0; mt < MT; ++mt) {
        #pragma unroll
        for (int r = 0; r < 4; ++r) {
            float x = acc[mt][r] + bias[mt * 16 + quad * 4 + r];
            if (RELU) x = fmaxf(x, 0.f);
            v[mt][r] = x;
            if (OMODE >= 2) ss += x * x;
        }
    }
    if (OMODE >= 2) {
        ss += __shfl_xor(ss, 16, 64);
        ss += __shfl_xor(ss, 32, 64);
    }
    unsigned short* orow = out + ((size_t)b * N + s) * OUTW;
    #pragma unroll
    for (int mt = 0; mt < MT; ++mt) {
        uint2 p;
        p.x = pack2(v[mt][0], v[mt][1]);
        p.y = pack2(v[mt][2], v[mt][3]);
        *(uint2*)(orow + mt * 16 + quad * 4) = p;
    }
    if (OMODE == 1 && quad == 0) {
        uint4 z = {0u, 0u, 0u, 0u};
        *(uint4*)(orow + 80) = z;
        *(uint4*)(orow + 88) = z;
    }
    if (OMODE >= 2 && quad == 0) {
        float e80 = (OMODE == 2) ? (-0.5f * ss) : 1.0f;
        float e81 = (OMODE == 2) ? 1.0f : (-0.5f * ss);
        uint4 z0 = {pack2(e80, e81), 0u, 0u, 0u};
        uint4 z1 = {0u, 0u, 0u, 0u};
        *(uint4*)(orow + 80) = z0;
        *(uint4*)(orow + 88) = z1;
    }
}

// ---------------- qk MFMA -> bf16 logits lgt[b][t1][s] ----------------
__global__ __launch_bounds__(64) void attn_logits_kernel(
        const unsigned short* __restrict__ qT, const unsigned short* __restrict__ kT,
        unsigned short* __restrict__ lgt) {
    const int b = blockIdx.y;
    const int t10 = blockIdx.x * 16;
    const int lane = threadIdx.x;
    const int l15 = lane & 15, quad = lane >> 4;

    const unsigned short* qrow = qT + ((size_t)b * T1_ + t10 + l15) * 96;
    short8 af[3];
    #pragma unroll
    for (int kc = 0; kc < 3; ++kc)
        af[kc] = *(const short8*)(qrow + kc * 32 + quad * 8);

    f32x4 acc[25];
    #pragma unroll
    for (int ns = 0; ns < 25; ++ns) acc[ns] = (f32x4){0.f, 0.f, 0.f, 0.f};
    const unsigned short* kbase = kT + (size_t)b * T2_ * 96 + l15 * 96 + quad * 8;
    #pragma unroll
    for (int ns = 0; ns < 25; ++ns) {
        #pragma unroll
        for (int kc = 0; kc < 3; ++kc) {
            short8 bf = *(const short8*)(kbase + ns * 16 * 96 + kc * 32);
            acc[ns] = __builtin_amdgcn_mfma_f32_16x16x32_bf16(af[kc], bf, acc[ns], 0, 0, 0);
        }
    }
    const float K2T = 2.0f * TEMP;
    #pragma unroll
    for (int r = 0; r < 4; ++r) {
        unsigned short* orow = lgt + ((size_t)b * T1_ + t10 + quad * 4 + r) * T2_;
        #pragma unroll
        for (int ns = 0; ns < 25; ++ns)
            orow[ns * 16 + l15] = f2bf(K2T * acc[ns][r]);
    }
}

// ---------------- streaming double-softmax: lgt+prior+mask -> attn, lp ----------------
// 4 waves / block, 1 row / wave. Fully coalesced; 51200 waves.
__global__ __launch_bounds__(256) void softmax_kernel(
        const unsigned short* __restrict__ lgt, const int* __restrict__ mask,
        const float* __restrict__ prior,
        float* __restrict__ attn_out, float* __restrict__ lp_out) {
    const int b = blockIdx.y;
    const int t1 = blockIdx.x * 4 + (threadIdx.x >> 6);
    const int lane = threadIdx.x & 63;
    const unsigned short* lrow = lgt + ((size_t)b * T1_ + t1) * T2_;
    const float* prow = prior + ((size_t)b * T1_ + t1) * T2_;
    const int* mrow = mask + b * T2_;

    float l[7], pe[7], kp[7];
    #pragma unroll
    for (int j = 0; j < 7; ++j) {
        int s = lane + 64 * j;
        bool v = (j < 6) || (lane < 16);
        l[j]  = v ? bf2f(lrow[s]) : -1e30f;
        pe[j] = v ? (prow[s] + 1e-8f) : 1.f;
        kp[j] = (v && !mrow[v ? s : 0]) ? 1.f : 0.f;
    }
    float m = l[0];
    #pragma unroll
    for (int j = 1; j < 7; ++j) m = fmaxf(m, l[j]);
    #pragma unroll
    for (int off = 1; off <= 32; off <<= 1) m = fmaxf(m, __shfl_xor(m, off, 64));
    float e1[7];
    float sum = 0.f;
    #pragma unroll
    for (int j = 0; j < 7; ++j) { float e = __expf(l[j] - m); e1[j] = e; sum += e; }
    #pragma unroll
    for (int off = 1; off <= 32; off <<= 1) sum += __shfl_xor(sum, off, 64);
    const float lse = m + __logf(sum);

    float u[7];
    float sum2 = 0.f;
    #pragma unroll
    for (int j = 0; j < 7; ++j) {
        float uu = e1[j] * pe[j] * kp[j];
        u[j] = uu;
        sum2 += uu;
    }
    #pragma unroll
    for (int off = 1; off <= 32; off <<= 1) sum2 += __shfl_xor(sum2, off, 64);
    const float inv = 1.f / sum2;

    float* lpr = lp_out + ((size_t)b * T1_ + t1) * T2_;
    float* atr = attn_out + ((size_t)b * T1_ + t1) * T2_;
    #pragma unroll
    for (int j = 0; j < 7; ++j) {
        int s = lane + 64 * j;
        bool v = (j < 6) || (lane < 16);
        if (v) {
            lpr[s] = l[j] - lse + __logf(pe[j]);
            atr[s] = u[j] * inv;
        }
    }
}

extern "C" void kernel_launch(void* const* d_in, const int* in_sizes, int n_in,
                              void* d_out, int out_size, void* d_ws, size_t ws_size,
                              hipStream_t stream) {
    const float* queries = (const float*)d_in[0];
    const float* keys    = (const float*)d_in[1];
    const int*   mask    = (const int*)d_in[2];
    const float* prior   = (const float*)d_in[3];
    const float* se      = (const float*)d_in[4];
    const float* Wk1 = (const float*)d_in[5];
    const float* bk1 = (const float*)d_in[6];
    const float* Wk2 = (const float*)d_in[7];
    const float* bk2 = (const float*)d_in[8];
    const float* Wq1 = (const float*)d_in[9];
    const float* bq1 = (const float*)d_in[10];
    const float* Wq2 = (const float*)d_in[11];
    const float* bq2 = (const float*)d_in[12];
    const float* Wq3 = (const float*)d_in[13];
    const float* bq3 = (const float*)d_in[14];
    const float* Wks = (const float*)d_in[15];
    const float* bks = (const float*)d_in[16];
    const float* Wqs = (const float*)d_in[17];
    const float* bqs = (const float*)d_in[18];

    // workspace (float units), peak 14,240,768 fl = 57.0 MB (unchanged):
    // head: kb 0 | qb 16,384 | Ab1 18,944 | A2 805,376 | A3 846,336 | A4 869,376
    //       A5 875,776 | qT 879,616 | kT 3,337,216 | D = 3,951,616
    // keys: Xk @D (3,735,552) | k1c @D+3,735,552 (6,553,600)
    // q:    Xq1 @D (2,460,672) | Xq2 @D+2,460,672 (4,096,000) | Xq3 @D
    // attn: lgt @D (10,240,000 fl as bf16) overlays dead scratch
    float* ws = (float*)d_ws;
    float* kb = ws;
    float* qb = ws + 16384;
    unsigned short* Ab1 = (unsigned short*)(ws + 18944);
    unsigned short* A2  = (unsigned short*)(ws + 805376);
    unsigned short* A3  = (unsigned short*)(ws + 846336);
    unsigned short* A4  = (unsigned short*)(ws + 869376);
    unsigned short* A5  = (unsigned short*)(ws + 875776);
    unsigned short* qT  = (unsigned short*)(ws + 879616);
    unsigned short* kT  = (unsigned short*)(ws + 3337216);
    const size_t D = 3951616;
    unsigned short* Xk  = (unsigned short*)(ws + D);
    unsigned short* k1c = (unsigned short*)(ws + D + 3735552);
    unsigned short* Xq1 = (unsigned short*)(ws + D);
    unsigned short* Xq2 = (unsigned short*)(ws + D + 2460672);
    unsigned short* Xq3 = (unsigned short*)(ws + D);
    unsigned short* lgt = (unsigned short*)(ws + D);

    float* attn_out = (float*)d_out;
    float* lp_out   = attn_out + (size_t)B_ * T1_ * T2_;

    bias_kernel<<<dim3(74), dim3(256), 0, stream>>>(se, Wks, bks, Wqs, bqs, kb, qb);
    cast_weights_kernel<<<dim3(6724), dim3(256), 0, stream>>>(Wk1, Wk2, Wq1, Wq2, Wq3,
                                                              Ab1, A2, A3, A4, A5);
    // keys path
    castXk_kernel<<<dim3(8, 8, 32), dim3(256), 0, stream>>>(keys, kb, Xk);
    conv1k_mfma<<<dim3(7, 8, 32), dim3(256), 0, stream>>>(Ab1, Xk, bk1, k1c);
    gemm_cl<5, 32, 0, false, 2, 1024, 96, 400, 400>
        <<<dim3(7, 32), 256, 0, stream>>>(A2, k1c, bk2, kT);
    // query path
    castXq_kernel<<<dim3(25, 32), dim3(256), 0, stream>>>(queries, qb, Xq1);
    gemm_cl<10, 9, 3, true, 0, 96, 160, 1600, 1602>
        <<<dim3(25, 32), 256, 0, stream>>>(A3, Xq1, bq1, Xq2);
    gemm_cl<5, 5, 0, true, 1, 160, 96, 1600, 1600>
        <<<dim3(25, 32), 256, 0, stream>>>(A4, Xq2, bq2, Xq3);
    gemm_cl<5, 3, 0, false, 3, 96, 96, 1600, 1600>
        <<<dim3(25, 32), 256, 0, stream>>>(A5, Xq3, bq3, qT);
    // attention: MFMA logits (bf16) then streaming double-softmax
    attn_logits_kernel<<<dim3(100, 32), dim3(64), 0, stream>>>(qT, kT, lgt);
    softmax_kernel<<<dim3(400, 32), dim3(256), 0, stream>>>(lgt, mask, prior, attn_out, lp_out);
}